// Round 5
// baseline (292.322 us; speedup 1.0000x reference)
//
#include <hip/hip_runtime.h>
#include <hip/hip_fp16.h>

// VoxelGrid trilinear sampling, MI355X.
// Round 5: cell-centric fp16 table (one 16 B record = all 8 corners) + 
// 4 points per thread for memory-level parallelism. Round-4 analysis:
// gather is L2-miss LATENCY bound (~1 outstanding miss/wave, ~400cy L3);
// 4 independent gathers/thread -> ~128 outstanding misses/CU -> fill-BW regime.

constexpr int SX = 200, SY = 200, SZ = 50;
constexpr int NVOX = SX * SY * SZ;            // 2,000,000
constexpr int CX = SX - 1, CY = SY - 1, CZ = SZ - 1;  // 199,199,49
constexpr int NCELL = CX * CY * CZ;           // 1,940,449
constexpr int PPT = 4;                        // points per thread
constexpr int BLK = 256;
constexpr int PPB = BLK * PPT;                // 1024 points per block

__global__ __launch_bounds__(256) void build_cells(
    const float* __restrict__ grid, uint4* __restrict__ rec)
{
    int i = blockIdx.x * 256 + threadIdx.x;
    if (i >= NCELL) return;
    int cz = i % CZ;
    int tmp = i / CZ;
    int cy = tmp % CY;
    int cx = tmp / CY;

    const float* g00 = grid + (cx * SY + cy) * SZ + cz;
    const float* g01 = g00 + SZ;        // y+1
    const float* g10 = g00 + SY * SZ;   // x+1
    const float* g11 = g10 + SZ;

    union { __half2 h[4]; uint4 u; } p;
    p.h[0] = __floats2half2_rn(g00[0], g00[1]);
    p.h[1] = __floats2half2_rn(g01[0], g01[1]);
    p.h[2] = __floats2half2_rn(g10[0], g10[1]);
    p.h[3] = __floats2half2_rn(g11[0], g11[1]);
    rec[i] = p.u;
}

__global__ __launch_bounds__(256) void voxel_trilinear_cell4(
    const float* __restrict__ x,      // [N,3]
    const uint4* __restrict__ rec,    // [NCELL] packed cell records
    float* __restrict__ out,          // [2*N]: sigma | alpha
    int n)
{
    __shared__ float xs[3 * PPB];     // 12 KB
    int tid = threadIdx.x;
    long long base = (long long)blockIdx.x * PPB;

    // cooperative float4 staging of this block's 1024 points (12 KB)
    if (base + PPB <= n) {
        const float4* xg = (const float4*)(x + base * 3);
        float4* xl = (float4*)xs;
        #pragma unroll
        for (int j = 0; j < 3; ++j)
            xl[tid + BLK * j] = xg[tid + BLK * j];
    } else {
        for (int j = tid; j < 3 * PPB; j += BLK) {
            long long g = base * 3 + j;
            xs[j] = (g < 3LL * n) ? x[g] : 0.0f;
        }
    }
    __syncthreads();

    int   cell[PPT];
    float ux[PPT], uy[PPT], uz[PPT];
    bool  valid[PPT];

    #pragma unroll
    for (int k = 0; k < PPT; ++k) {
        int p = tid + BLK * k;
        float ix = (xs[3 * p + 0] + 4.0f) * 25.0f;
        float iy = (xs[3 * p + 1] + 4.0f) * 25.0f;
        float iz = (xs[3 * p + 2] + 1.0f) * 25.0f;
        valid[k] = (ix >= 0.0f) & (ix <= (float)(SX - 1)) &
                   (iy >= 0.0f) & (iy <= (float)(SY - 1)) &
                   (iz >= 0.0f) & (iz <= (float)(SZ - 1));
        int cx = min(max((int)floorf(ix), 0), SX - 2);
        int cy = min(max((int)floorf(iy), 0), SY - 2);
        int cz = min(max((int)floorf(iz), 0), SZ - 2);
        ux[k] = ix - (float)cx;
        uy[k] = iy - (float)cy;
        uz[k] = iz - (float)cz;
        cell[k] = (cx * CY + cy) * CZ + cz;
    }

    // 4 independent gathers — issued back-to-back for MLP
    uint4 pk[PPT];
    #pragma unroll
    for (int k = 0; k < PPT; ++k)
        pk[k] = rec[cell[k]];

    #pragma unroll
    for (int k = 0; k < PPT; ++k) {
        union { uint4 u; __half2 h[4]; } p;
        p.u = pk[k];
        float2 f00 = __half22float2(p.h[0]);  // (x0,y0): v000,v001
        float2 f01 = __half22float2(p.h[1]);  // (x0,y1)
        float2 f10 = __half22float2(p.h[2]);  // (x1,y0)
        float2 f11 = __half22float2(p.h[3]);  // (x1,y1)
        float vz = 1.0f - uz[k], vy = 1.0f - uy[k], vx = 1.0f - ux[k];
        float c00 = f00.x * vz + f00.y * uz[k];
        float c01 = f01.x * vz + f01.y * uz[k];
        float c10 = f10.x * vz + f10.y * uz[k];
        float c11 = f11.x * vz + f11.y * uz[k];
        float c0 = c00 * vy + c01 * uy[k];
        float c1 = c10 * vy + c11 * uy[k];
        float acc = c0 * vx + c1 * ux[k];

        long long i = base + tid + BLK * k;
        if (i < n) {
            out[i] = valid[k] ? acc : 0.0f;  // sigma
            out[n + i] = 0.0f;               // alpha (do_alpha=False)
        }
    }
}

// ---- fallback (fp16 z-pair table, 4 MB) for small ws ----
__global__ __launch_bounds__(256) void convert_grid_fp16(
    const float* __restrict__ grid, __half* __restrict__ t)
{
    int i = blockIdx.x * 256 + threadIdx.x;
    if (i < NVOX) t[i] = __float2half(grid[i]);
}

__device__ __forceinline__ float2 ldpair(const __half* __restrict__ t, int idx)
{
    __half2 h;
    __builtin_memcpy(&h, t + idx, sizeof(__half2));
    return __half22float2(h);
}

__global__ __launch_bounds__(256) void voxel_trilinear_pair(
    const float* __restrict__ x, const __half* __restrict__ t,
    float* __restrict__ out, int n)
{
    int i = blockIdx.x * 256 + threadIdx.x;
    if (i >= n) return;
    float ix = (x[3 * i + 0] + 4.0f) * 25.0f;
    float iy = (x[3 * i + 1] + 4.0f) * 25.0f;
    float iz = (x[3 * i + 2] + 1.0f) * 25.0f;
    bool valid = (ix >= 0.0f) & (ix <= (float)(SX - 1)) &
                 (iy >= 0.0f) & (iy <= (float)(SY - 1)) &
                 (iz >= 0.0f) & (iz <= (float)(SZ - 1));
    float fx = floorf(ix), fy = floorf(iy), fz = floorf(iz);
    int ax = min(max((int)fx, 0), SX - 1);
    int ay = min(max((int)fy, 0), SY - 1);
    int bx = min(ax + 1, SX - 1);
    int by = min(ay + 1, SY - 1);
    int zc = min(max((int)fz, 0), SZ - 2);
    float u = iz - (float)zc, su = 1.0f - u;
    float tx = ix - fx, ty = iy - fy;
    float sx = 1.0f - tx, sy = 1.0f - ty;
    int r00 = (ax * SY + ay) * SZ + zc;
    int r01 = (ax * SY + by) * SZ + zc;
    int r10 = (bx * SY + ay) * SZ + zc;
    int r11 = (bx * SY + by) * SZ + zc;
    float2 p00 = ldpair(t, r00), p01 = ldpair(t, r01);
    float2 p10 = ldpair(t, r10), p11 = ldpair(t, r11);
    float c00 = p00.x * su + p00.y * u;
    float c01 = p01.x * su + p01.y * u;
    float c10 = p10.x * su + p10.y * u;
    float c11 = p11.x * su + p11.y * u;
    float c0 = c00 * sy + c01 * ty;
    float c1 = c10 * sy + c11 * ty;
    out[i] = valid ? (c0 * sx + c1 * tx) : 0.0f;
    out[n + i] = 0.0f;
}

extern "C" void kernel_launch(void* const* d_in, const int* in_sizes, int n_in,
                              void* d_out, int out_size, void* d_ws, size_t ws_size,
                              hipStream_t stream) {
    const float* x = (const float*)d_in[0];
    const float* grid = (const float*)d_in[1];
    float* out = (float*)d_out;
    int n = in_sizes[0] / 3;  // 8388608

    if (ws_size >= (size_t)NCELL * sizeof(uint4)) {
        uint4* rec = (uint4*)d_ws;
        build_cells<<<(NCELL + 255) / 256, 256, 0, stream>>>(grid, rec);
        int blocks = (n + PPB - 1) / PPB;
        voxel_trilinear_cell4<<<blocks, BLK, 0, stream>>>(x, rec, out, n);
    } else if (ws_size >= (size_t)NVOX * sizeof(__half)) {
        __half* t = (__half*)d_ws;
        convert_grid_fp16<<<(NVOX + 255) / 256, 256, 0, stream>>>(grid, t);
        voxel_trilinear_pair<<<(n + 255) / 256, 256, 0, stream>>>(x, t, out, n);
    }
}